// Round 1
// baseline (909.160 us; speedup 1.0000x reference)
//
#include <hip/hip_runtime.h>

constexpr int NGRAPH = 64;

// ---------------- concat x||pos -> h0 [N,16] ----------------
__global__ void concat_k(const float* __restrict__ x, const float* __restrict__ pos,
                         float* __restrict__ h0, int N) {
    int n = blockIdx.x * blockDim.x + threadIdx.x;
    if (n >= N) return;
    const float4* x4 = (const float4*)(x + (size_t)n * 8);
    const float4* p4 = (const float4*)(pos + (size_t)n * 8);
    float4* o4 = (float4*)(h0 + (size_t)n * 16);
    o4[0] = x4[0]; o4[1] = x4[1]; o4[2] = p4[0]; o4[3] = p4[1];
}

// ---------------- degree count ----------------
__global__ void deg_k(const int* __restrict__ dst, int* __restrict__ deg, int E) {
    int e = blockIdx.x * blockDim.x + threadIdx.x;
    if (e < E) atomicAdd(&deg[dst[e]], 1);
}

// ---------------- 3-kernel exclusive scan over deg -> offs ----------------
__global__ void scan1_k(const int* __restrict__ deg, int* __restrict__ offs,
                        int* __restrict__ partials, int N) {
    __shared__ int sm[512];
    int t = threadIdx.x;
    int i = blockIdx.x * 512 + t;
    int v = (i < N) ? deg[i] : 0;
    sm[t] = v;
    __syncthreads();
    int acc = v;
    for (int d = 1; d < 512; d <<= 1) {
        int add = (t >= d) ? sm[t - d] : 0;
        __syncthreads();
        acc += add;
        sm[t] = acc;
        __syncthreads();
    }
    if (i < N) offs[i] = acc - v;          // block-local exclusive
    if (t == 511) partials[blockIdx.x] = acc;  // block total
}

__global__ void scan2_k(int* __restrict__ partials, int nb) {
    if (threadIdx.x == 0) {
        int run = 0;
        for (int b = 0; b < nb; ++b) { int v = partials[b]; partials[b] = run; run += v; }
    }
}

__global__ void scan3_k(int* __restrict__ offs, const int* __restrict__ partials,
                        int* __restrict__ cursor, int N, int E) {
    int i = blockIdx.x * 512 + threadIdx.x;
    if (i < N) {
        int o = offs[i] + partials[blockIdx.x];
        offs[i] = o;
        cursor[i] = o;
    }
    if (i == 0) offs[N] = E;
}

// ---------------- dinv ----------------
__global__ void dinv_k(const int* __restrict__ deg, float* __restrict__ dinv, int N) {
    int n = blockIdx.x * blockDim.x + threadIdx.x;
    if (n < N) dinv[n] = 1.0f / sqrtf((float)deg[n] + 1.0f);
}

// ---------------- CSR fill (src list grouped by dst) ----------------
__global__ void fill_k(const int* __restrict__ src, const int* __restrict__ dst,
                       int* __restrict__ cursor, int* __restrict__ csr, int E) {
    int e = blockIdx.x * blockDim.x + threadIdx.x;
    if (e >= E) return;
    int d = dst[e];
    int p = atomicAdd(&cursor[d], 1);
    csr[p] = src[e];
}

// ---------------- aggregation: out[n] = dinv[n]*sum(dinv[s]*h[s]) + dinv[n]^2*h[n] (+bias) ----------------
template <int DIM, int GSZ>
__global__ void agg_k(const float* __restrict__ h, const int* __restrict__ offs,
                      const int* __restrict__ csr, const float* __restrict__ dinv,
                      const float* __restrict__ bias, float* __restrict__ out, int N) {
    constexpr int GPB = 256 / GSZ;
    int g = blockIdx.x * GPB + threadIdx.x / GSZ;
    int f = threadIdx.x % GSZ;
    if (g >= N) return;
    int beg = offs[g], end = offs[g + 1];
    float acc = 0.f;
    for (int j = beg; j < end; ++j) {
        int s = csr[j];
        float w = dinv[s];
        float hv = (f < DIM) ? h[(size_t)s * DIM + f] : 0.f;
        acc = fmaf(w, hv, acc);
    }
    if (f < DIM) {
        float dn = dinv[g];
        float v = fmaf(dn, acc, dn * dn * h[(size_t)g * DIM + f]);
        if (bias) v += bias[f];
        out[(size_t)g * DIM + f] = v;
    }
}

// ---------------- dense layer: out = [relu](g @ W [+ b]) ----------------
template <int K, int OUT, int OP, bool RELU, bool BIAS>
__global__ void gemm_k(const float* __restrict__ gin, const float* __restrict__ W,
                       const float* __restrict__ b, float* __restrict__ out, int N) {
    __shared__ float Wl[K * OUT];
    constexpr int NPB = 256 / OP;
    int tid = threadIdx.x;
    for (int i = tid; i < K * OUT; i += 256) Wl[i] = W[i];
    __syncthreads();
    int node = blockIdx.x * NPB + tid / OP;
    int j = tid % OP;
    if (node >= N || j >= OUT) return;
    const float* row = gin + (size_t)node * K;
    float acc = BIAS ? b[j] : 0.f;
#pragma unroll
    for (int k = 0; k < K; ++k) acc = fmaf(row[k], Wl[k * OUT + j], acc);
    if (RELU) acc = fmaxf(acc, 0.f);
    out[(size_t)node * OUT + j] = acc;
}

// ---------------- per-graph mean pool, stage 1: partial sums ----------------
__global__ void pool_k(const float* __restrict__ h4, const int* __restrict__ batch,
                       float* __restrict__ pool, int N) {
    __shared__ float lp[NGRAPH * 12];
    int tid = threadIdx.x;
    for (int i = tid; i < NGRAPH * 12; i += 256) lp[i] = 0.f;
    __syncthreads();
    int n = blockIdx.x * 256 + tid;
    if (n < N) {
        int gr = batch[n];
        const float* row = h4 + (size_t)n * 10;
#pragma unroll
        for (int f = 0; f < 10; ++f) atomicAdd(&lp[gr * 12 + f], row[f]);
        atomicAdd(&lp[gr * 12 + 10], 1.f);
    }
    __syncthreads();
    for (int i = tid; i < NGRAPH * 12; i += 256) {
        int gr = i / 12, c = i % 12;
        float v = lp[i];
        if (c < 11 && v != 0.f) atomicAdd(&pool[gr * 11 + c], v);
    }
}

// ---------------- final divide ----------------
__global__ void final_k(const float* __restrict__ pool, float* __restrict__ out) {
    int i = blockIdx.x * blockDim.x + threadIdx.x;
    if (i >= NGRAPH * 10) return;
    int g = i / 10, f = i % 10;
    float c = pool[g * 11 + 10];
    out[i] = pool[g * 11 + f] / fmaxf(c, 1.f);
}

extern "C" void kernel_launch(void* const* d_in, const int* in_sizes, int n_in,
                              void* d_out, int out_size, void* d_ws, size_t ws_size,
                              hipStream_t stream) {
    const float* x   = (const float*)d_in[0];
    const float* pos = (const float*)d_in[1];
    const int* eidx  = (const int*)d_in[2];
    const int* batch = (const int*)d_in[3];
    const float* W1 = (const float*)d_in[4];  const float* b1 = (const float*)d_in[5];
    const float* W2 = (const float*)d_in[6];  const float* b2 = (const float*)d_in[7];
    const float* W3 = (const float*)d_in[8];  const float* b3 = (const float*)d_in[9];
    const float* W4 = (const float*)d_in[10]; const float* b4 = (const float*)d_in[11];

    const int N = in_sizes[0] / 8;
    const int E = in_sizes[2] / 2;
    const int* src = eidx;
    const int* dst = eidx + E;

    char* p = (char*)d_ws;
    auto alloc = [&](size_t bytes) { char* r = p; p += (bytes + 255) & ~255ull; return r; };
    int*   deg      = (int*)alloc((size_t)N * 4);
    int*   offs     = (int*)alloc((size_t)(N + 1) * 4);
    int*   cursor   = (int*)alloc((size_t)N * 4);
    int*   partials = (int*)alloc(4096);
    float* dinv     = (float*)alloc((size_t)N * 4);
    int*   csr      = (int*)alloc((size_t)E * 4);
    float* bufA     = (float*)alloc((size_t)N * 128 * 4);
    float* bufB     = (float*)alloc((size_t)N * 64 * 4);
    float* pool     = (float*)alloc(NGRAPH * 11 * 4);

    hipMemsetAsync(deg, 0, (size_t)N * 4, stream);
    hipMemsetAsync(pool, 0, NGRAPH * 11 * 4, stream);

    concat_k<<<(N + 255) / 256, 256, 0, stream>>>(x, pos, bufA, N);
    deg_k<<<(E + 255) / 256, 256, 0, stream>>>(dst, deg, E);

    const int nb = (N + 511) / 512;
    scan1_k<<<nb, 512, 0, stream>>>(deg, offs, partials, N);
    scan2_k<<<1, 64, 0, stream>>>(partials, nb);
    scan3_k<<<nb, 512, 0, stream>>>(offs, partials, cursor, N, E);
    dinv_k<<<(N + 255) / 256, 256, 0, stream>>>(deg, dinv, N);
    fill_k<<<(E + 255) / 256, 256, 0, stream>>>(src, dst, cursor, csr, E);

    // Layer 1: g = A_hat h0 (dim16), h1 = relu(g @ W1 + b1)  [16->32]
    agg_k<16, 16><<<(N + 15) / 16, 256, 0, stream>>>(bufA, offs, csr, dinv, nullptr, bufB, N);
    gemm_k<16, 32, 32, true, true><<<(N + 7) / 8, 256, 0, stream>>>(bufB, W1, b1, bufA, N);

    // Layer 2: [32->64]
    agg_k<32, 32><<<(N + 7) / 8, 256, 0, stream>>>(bufA, offs, csr, dinv, nullptr, bufB, N);
    gemm_k<32, 64, 64, true, true><<<(N + 3) / 4, 256, 0, stream>>>(bufB, W2, b2, bufA, N);

    // Layer 3: [64->128]
    agg_k<64, 64><<<(N + 3) / 4, 256, 0, stream>>>(bufA, offs, csr, dinv, nullptr, bufB, N);
    gemm_k<64, 128, 128, true, true><<<(N + 1) / 2, 256, 0, stream>>>(bufB, W3, b3, bufA, N);

    // Layer 4: t = h3 @ W4 (128->10), then h4 = A_hat t + b4 (aggregate small dim)
    gemm_k<128, 10, 16, false, false><<<(N + 15) / 16, 256, 0, stream>>>(bufA, W4, b4, bufB, N);
    agg_k<10, 16><<<(N + 15) / 16, 256, 0, stream>>>(bufB, offs, csr, dinv, b4, bufA, N);

    // Mean pool per graph
    pool_k<<<(N + 255) / 256, 256, 0, stream>>>(bufA, batch, pool, N);
    final_k<<<3, 256, 0, stream>>>(pool, (float*)d_out);
}

// Round 6
// 643.025 us; speedup vs baseline: 1.4139x; 1.4139x over previous
//
#include <hip/hip_runtime.h>

constexpr int NGRAPH = 64;

// ---------------- concat x||pos -> h0 [N,16] ----------------
__global__ void concat_k(const float* __restrict__ x, const float* __restrict__ pos,
                         float* __restrict__ h0, int N) {
    int n = blockIdx.x * blockDim.x + threadIdx.x;
    if (n >= N) return;
    const float4* x4 = (const float4*)(x + (size_t)n * 8);
    const float4* p4 = (const float4*)(pos + (size_t)n * 8);
    float4* o4 = (float4*)(h0 + (size_t)n * 16);
    o4[0] = x4[0]; o4[1] = x4[1]; o4[2] = p4[0]; o4[3] = p4[1];
}

// ---------------- degree count ----------------
__global__ void deg_k(const int* __restrict__ dst, int* __restrict__ deg, int E) {
    int e = blockIdx.x * blockDim.x + threadIdx.x;
    if (e < E) atomicAdd(&deg[dst[e]], 1);
}

// ---------------- scan: block-local exclusive + block totals ----------------
__global__ void scan1_k(const int* __restrict__ deg, int* __restrict__ offs,
                        int* __restrict__ partials, int N) {
    __shared__ int sm[512];
    int t = threadIdx.x;
    int i = blockIdx.x * 512 + t;
    int v = (i < N) ? deg[i] : 0;
    sm[t] = v;
    __syncthreads();
    int acc = v;
    for (int d = 1; d < 512; d <<= 1) {
        int add = (t >= d) ? sm[t - d] : 0;
        __syncthreads();
        acc += add;
        sm[t] = acc;
        __syncthreads();
    }
    if (i < N) offs[i] = acc - v;
    if (t == 511) partials[blockIdx.x] = acc;
}

// parallel exclusive scan of block totals (nb <= 512)
__global__ void scan2b_k(int* __restrict__ partials, int nb) {
    __shared__ int sm[512];
    int t = threadIdx.x;
    int v = (t < nb) ? partials[t] : 0;
    sm[t] = v;
    __syncthreads();
    int acc = v;
    for (int d = 1; d < 512; d <<= 1) {
        int add = (t >= d) ? sm[t - d] : 0;
        __syncthreads();
        acc += add;
        sm[t] = acc;
        __syncthreads();
    }
    if (t < nb) partials[t] = acc - v;
}

__global__ void scan3_k(int* __restrict__ offs, const int* __restrict__ partials,
                        int* __restrict__ cursor, int N, int E) {
    int i = blockIdx.x * 512 + threadIdx.x;
    if (i < N) {
        int o = offs[i] + partials[blockIdx.x];
        offs[i] = o;
        cursor[i] = o;
    }
    if (i == 0) offs[N] = E;
}

// ---------------- dinv ----------------
__global__ void dinv_k(const int* __restrict__ deg, float* __restrict__ dinv, int N) {
    int n = blockIdx.x * blockDim.x + threadIdx.x;
    if (n < N) dinv[n] = 1.0f / sqrtf((float)deg[n] + 1.0f);
}

// ---------------- CSR fill (src grouped by dst) ----------------
__global__ void fill_k(const int* __restrict__ src, const int* __restrict__ dst,
                       int* __restrict__ cursor, int* __restrict__ csr, int E) {
    int e = blockIdx.x * blockDim.x + threadIdx.x;
    if (e >= E) return;
    int d = dst[e];
    int p = atomicAdd(&cursor[d], 1);
    csr[p] = src[e];
}

// ---------------- fused layer: agg(K) in LDS -> gemm(K->OUT)+bias+relu [-> gemm(128->10)] ----------------
// NPB = 1024/K nodes per tile; JPT=4 outputs/thread, 2 nodes/thread in gemm phase.
template <int K, int OUT, bool RELU, bool FUSE4>
__global__ __launch_bounds__(256) void layer_k(
    const float* __restrict__ h, const int* __restrict__ offs, const int* __restrict__ csr,
    const float* __restrict__ dinv, const float* __restrict__ W, const float* __restrict__ bias,
    const float* __restrict__ W4, float* __restrict__ out, int N, int ntiles)
{
    constexpr int NPB  = 1024 / K;    // nodes per tile (gather phase covers all in one pass)
    constexpr int RSTR = K + 4;       // padded LDS row stride (floats) — breaks bank aliasing
    constexpr int JG   = OUT / 4;     // j-groups (each thread owns 4 consecutive outputs)
    constexpr int NTHN = 1024 / OUT;  // nodes covered per gemm pass
    constexpr int GA   = K / 4;       // lanes per node in gather phase
    constexpr int ISTR = 132;         // inter row stride (padded 128)

    __shared__ float Wl[K * OUT];
    __shared__ float bl[OUT];
    __shared__ float rows[NPB * RSTR];
    __shared__ float W4l[FUSE4 ? 1280 : 1];
    __shared__ float inter[FUSE4 ? (1024 / K) * ISTR : 1];

    const int tid = threadIdx.x;
    for (int i = tid; i < K * OUT; i += 256) Wl[i] = W[i];
    for (int i = tid; i < OUT; i += 256) bl[i] = bias[i];
    if constexpr (FUSE4)
        for (int i = tid; i < 1280; i += 256) W4l[i] = W4[i];
    __syncthreads();

    const int anl = tid / GA;         // gather: node-local
    const int af4 = tid % GA;         // gather: float4 lane
    const int jg  = tid % JG;         // gemm: output group
    const int bnl = tid / JG;         // gemm: first node-local
    const float4 bfrag = *(const float4*)&bl[jg * 4];

    for (int tile = blockIdx.x; tile < ntiles; tile += gridDim.x) {
        const int base = tile * NPB;

        // ---- Phase A: aggregate node (base+anl) into LDS row ----
        {
            int g = base + anl;
            if (g < N) {
                int beg = offs[g], end = offs[g + 1];
                float4 acc = {0.f, 0.f, 0.f, 0.f};
                for (int j = beg; j < end; ++j) {
                    int s = csr[j];
                    float w = dinv[s];
                    float4 hv = ((const float4*)h)[(size_t)s * GA + af4];
                    acc.x = fmaf(w, hv.x, acc.x);
                    acc.y = fmaf(w, hv.y, acc.y);
                    acc.z = fmaf(w, hv.z, acc.z);
                    acc.w = fmaf(w, hv.w, acc.w);
                }
                float dn = dinv[g], dn2 = dn * dn;
                float4 hs = ((const float4*)h)[(size_t)g * GA + af4];
                float4 v;
                v.x = fmaf(dn, acc.x, dn2 * hs.x);
                v.y = fmaf(dn, acc.y, dn2 * hs.y);
                v.z = fmaf(dn, acc.z, dn2 * hs.z);
                v.w = fmaf(dn, acc.w, dn2 * hs.w);
                *(float4*)&rows[anl * RSTR + af4 * 4] = v;
            }
        }
        __syncthreads();

        // ---- Phase B: gemm from LDS, 2 nodes x 4 outputs per thread ----
        {
            const float* r0 = &rows[bnl * RSTR];
            const float* r1 = &rows[(bnl + NTHN) * RSTR];
            float4 a0 = bfrag, a1 = bfrag;
#pragma unroll
            for (int k = 0; k < K; k += 4) {
                float4 x0 = *(const float4*)&r0[k];
                float4 x1 = *(const float4*)&r1[k];
                float4 w0 = *(const float4*)&Wl[(k + 0) * OUT + jg * 4];
                float4 w1 = *(const float4*)&Wl[(k + 1) * OUT + jg * 4];
                float4 w2 = *(const float4*)&Wl[(k + 2) * OUT + jg * 4];
                float4 w3 = *(const float4*)&Wl[(k + 3) * OUT + jg * 4];
                a0.x = fmaf(x0.x, w0.x, a0.x); a0.y = fmaf(x0.x, w0.y, a0.y);
                a0.z = fmaf(x0.x, w0.z, a0.z); a0.w = fmaf(x0.x, w0.w, a0.w);
                a0.x = fmaf(x0.y, w1.x, a0.x); a0.y = fmaf(x0.y, w1.y, a0.y);
                a0.z = fmaf(x0.y, w1.z, a0.z); a0.w = fmaf(x0.y, w1.w, a0.w);
                a0.x = fmaf(x0.z, w2.x, a0.x); a0.y = fmaf(x0.z, w2.y, a0.y);
                a0.z = fmaf(x0.z, w2.z, a0.z); a0.w = fmaf(x0.z, w2.w, a0.w);
                a0.x = fmaf(x0.w, w3.x, a0.x); a0.y = fmaf(x0.w, w3.y, a0.y);
                a0.z = fmaf(x0.w, w3.z, a0.z); a0.w = fmaf(x0.w, w3.w, a0.w);
                a1.x = fmaf(x1.x, w0.x, a1.x); a1.y = fmaf(x1.x, w0.y, a1.y);
                a1.z = fmaf(x1.x, w0.z, a1.z); a1.w = fmaf(x1.x, w0.w, a1.w);
                a1.x = fmaf(x1.y, w1.x, a1.x); a1.y = fmaf(x1.y, w1.y, a1.y);
                a1.z = fmaf(x1.y, w1.z, a1.z); a1.w = fmaf(x1.y, w1.w, a1.w);
                a1.x = fmaf(x1.z, w2.x, a1.x); a1.y = fmaf(x1.z, w2.y, a1.y);
                a1.z = fmaf(x1.z, w2.z, a1.z); a1.w = fmaf(x1.z, w2.w, a1.w);
                a1.x = fmaf(x1.w, w3.x, a1.x); a1.y = fmaf(x1.w, w3.y, a1.y);
                a1.z = fmaf(x1.w, w3.z, a1.z); a1.w = fmaf(x1.w, w3.w, a1.w);
            }
            if (RELU) {
                a0.x = fmaxf(a0.x, 0.f); a0.y = fmaxf(a0.y, 0.f);
                a0.z = fmaxf(a0.z, 0.f); a0.w = fmaxf(a0.w, 0.f);
                a1.x = fmaxf(a1.x, 0.f); a1.y = fmaxf(a1.y, 0.f);
                a1.z = fmaxf(a1.z, 0.f); a1.w = fmaxf(a1.w, 0.f);
            }
            if constexpr (!FUSE4) {
                int g0 = base + bnl;
                int g1 = base + bnl + NTHN;
                if (g0 < N) *(float4*)&out[(size_t)g0 * OUT + jg * 4] = a0;
                if (g1 < N) *(float4*)&out[(size_t)g1 * OUT + jg * 4] = a1;
            } else {
                *(float4*)&inter[bnl * ISTR + jg * 4] = a0;
                *(float4*)&inter[(bnl + NTHN) * ISTR + jg * 4] = a1;
            }
        }

        // ---- Phase C (layer 3 only): t = inter @ W4, 128 -> 10 ----
        if constexpr (FUSE4) {
            __syncthreads();
            int nl = tid >> 4, j = tid & 15;
            int g = base + nl;
            if (j < 10 && g < N) {
                const float* iv = &inter[nl * ISTR];
                float acc = 0.f;
#pragma unroll
                for (int k = 0; k < 128; k += 4) {
                    float4 v = *(const float4*)&iv[k];
                    acc = fmaf(v.x, W4l[(k + 0) * 10 + j], acc);
                    acc = fmaf(v.y, W4l[(k + 1) * 10 + j], acc);
                    acc = fmaf(v.z, W4l[(k + 2) * 10 + j], acc);
                    acc = fmaf(v.w, W4l[(k + 3) * 10 + j], acc);
                }
                out[(size_t)g * 10 + j] = acc;
            }
        }
        __syncthreads();   // protect rows/inter before next tile overwrites
    }
}

// ---------------- fused agg(10) + bias + per-graph mean pool stage 1 ----------------
__global__ __launch_bounds__(256) void aggpool_k(
    const float* __restrict__ t, const int* __restrict__ offs, const int* __restrict__ csr,
    const float* __restrict__ dinv, const float* __restrict__ b4, const int* __restrict__ batch,
    float* __restrict__ pool, int N)
{
    __shared__ float lp[NGRAPH * 11];
    int tid = threadIdx.x;
    for (int i = tid; i < NGRAPH * 11; i += 256) lp[i] = 0.f;
    __syncthreads();
    int nl = tid >> 4, j = tid & 15;
    int g = blockIdx.x * 16 + nl;
    if (g < N) {
        if (j < 10) {
            int beg = offs[g], end = offs[g + 1];
            float acc = 0.f;
            for (int e = beg; e < end; ++e) {
                int s = csr[e];
                acc = fmaf(dinv[s], t[(size_t)s * 10 + j], acc);
            }
            float dn = dinv[g];
            float v = fmaf(dn, acc, dn * dn * t[(size_t)g * 10 + j]) + b4[j];
            atomicAdd(&lp[batch[g] * 11 + j], v);
        } else if (j == 10) {
            atomicAdd(&lp[batch[g] * 11 + 10], 1.f);
        }
    }
    __syncthreads();
    for (int i = tid; i < NGRAPH * 11; i += 256) {
        float v = lp[i];
        if (v != 0.f) atomicAdd(&pool[i], v);
    }
}

// ---------------- final divide ----------------
__global__ void final_k(const float* __restrict__ pool, float* __restrict__ out) {
    int i = blockIdx.x * blockDim.x + threadIdx.x;
    if (i >= NGRAPH * 10) return;
    int g = i / 10, f = i % 10;
    float c = pool[g * 11 + 10];
    out[i] = pool[g * 11 + f] / fmaxf(c, 1.f);
}

extern "C" void kernel_launch(void* const* d_in, const int* in_sizes, int n_in,
                              void* d_out, int out_size, void* d_ws, size_t ws_size,
                              hipStream_t stream) {
    const float* x   = (const float*)d_in[0];
    const float* pos = (const float*)d_in[1];
    const int* eidx  = (const int*)d_in[2];
    const int* batch = (const int*)d_in[3];
    const float* W1 = (const float*)d_in[4];  const float* b1 = (const float*)d_in[5];
    const float* W2 = (const float*)d_in[6];  const float* b2 = (const float*)d_in[7];
    const float* W3 = (const float*)d_in[8];  const float* b3 = (const float*)d_in[9];
    const float* W4 = (const float*)d_in[10]; const float* b4 = (const float*)d_in[11];

    const int N = in_sizes[0] / 8;
    const int E = in_sizes[2] / 2;
    const int* src = eidx;
    const int* dst = eidx + E;

    char* p = (char*)d_ws;
    auto alloc = [&](size_t bytes) { char* r = p; p += (bytes + 255) & ~255ull; return r; };
    int*   deg      = (int*)alloc((size_t)N * 4);
    int*   offs     = (int*)alloc((size_t)(N + 1) * 4);
    int*   cursor   = (int*)alloc((size_t)N * 4);
    int*   partials = (int*)alloc(512 * 4);
    float* dinv     = (float*)alloc((size_t)N * 4);
    int*   csr      = (int*)alloc((size_t)E * 4);
    float* h0       = (float*)alloc((size_t)N * 16 * 4);
    float* h1       = (float*)alloc((size_t)N * 32 * 4);
    float* h2       = (float*)alloc((size_t)N * 64 * 4);
    float* tbuf     = (float*)alloc((size_t)N * 10 * 4);
    float* pool     = (float*)alloc(NGRAPH * 11 * 4);

    hipMemsetAsync(deg, 0, (size_t)N * 4, stream);
    hipMemsetAsync(pool, 0, NGRAPH * 11 * 4, stream);

    concat_k<<<(N + 255) / 256, 256, 0, stream>>>(x, pos, h0, N);
    deg_k<<<(E + 255) / 256, 256, 0, stream>>>(dst, deg, E);

    const int nb = (N + 511) / 512;
    scan1_k<<<nb, 512, 0, stream>>>(deg, offs, partials, N);
    scan2b_k<<<1, 512, 0, stream>>>(partials, nb);
    scan3_k<<<nb, 512, 0, stream>>>(offs, partials, cursor, N, E);
    dinv_k<<<(N + 255) / 256, 256, 0, stream>>>(deg, dinv, N);
    fill_k<<<(E + 255) / 256, 256, 0, stream>>>(src, dst, cursor, csr, E);

    // Layer 1: agg16 + gemm 16->32 (+b1, relu) -> h1
    {
        int ntiles = (N + 63) / 64;
        int blocks = ntiles < 2048 ? ntiles : 2048;
        layer_k<16, 32, true, false><<<blocks, 256, 0, stream>>>(h0, offs, csr, dinv, W1, b1, nullptr, h1, N, ntiles);
    }
    // Layer 2: agg32 + gemm 32->64 (+b2, relu) -> h2
    {
        int ntiles = (N + 31) / 32;
        int blocks = ntiles < 2048 ? ntiles : 2048;
        layer_k<32, 64, true, false><<<blocks, 256, 0, stream>>>(h1, offs, csr, dinv, W2, b2, nullptr, h2, N, ntiles);
    }
    // Layer 3+4a: agg64 + gemm 64->128 (+b3, relu) + gemm 128->10 -> tbuf
    {
        int ntiles = (N + 15) / 16;
        int blocks = ntiles < 768 ? ntiles : 768;
        layer_k<64, 128, true, true><<<blocks, 256, 0, stream>>>(h2, offs, csr, dinv, W3, b3, W4, tbuf, N, ntiles);
    }
    // Layer 4b: agg10 + b4 + pool partials
    aggpool_k<<<(N + 15) / 16, 256, 0, stream>>>(tbuf, offs, csr, dinv, b4, batch, pool, N);
    final_k<<<3, 256, 0, stream>>>(pool, (float*)d_out);
}

// Round 7
// 535.510 us; speedup vs baseline: 1.6977x; 1.2008x over previous
//
#include <hip/hip_runtime.h>

constexpr int NGRAPH = 64;

// ---------------- concat x||pos -> h0 [N,16] ----------------
__global__ void concat_k(const float* __restrict__ x, const float* __restrict__ pos,
                         float* __restrict__ h0, int N) {
    int n = blockIdx.x * blockDim.x + threadIdx.x;
    if (n >= N) return;
    const float4* x4 = (const float4*)(x + (size_t)n * 8);
    const float4* p4 = (const float4*)(pos + (size_t)n * 8);
    float4* o4 = (float4*)(h0 + (size_t)n * 16);
    o4[0] = x4[0]; o4[1] = x4[1]; o4[2] = p4[0]; o4[3] = p4[1];
}

// ---------------- degree count ----------------
__global__ void deg_k(const int* __restrict__ dst, int* __restrict__ deg, int E) {
    int e = blockIdx.x * blockDim.x + threadIdx.x;
    if (e < E) atomicAdd(&deg[dst[e]], 1);
}

// ---------------- scan: block-local exclusive + block totals ----------------
__global__ void scan1_k(const int* __restrict__ deg, int* __restrict__ offs,
                        int* __restrict__ partials, int N) {
    __shared__ int sm[512];
    int t = threadIdx.x;
    int i = blockIdx.x * 512 + t;
    int v = (i < N) ? deg[i] : 0;
    sm[t] = v;
    __syncthreads();
    int acc = v;
    for (int d = 1; d < 512; d <<= 1) {
        int add = (t >= d) ? sm[t - d] : 0;
        __syncthreads();
        acc += add;
        sm[t] = acc;
        __syncthreads();
    }
    if (i < N) offs[i] = acc - v;
    if (t == 511) partials[blockIdx.x] = acc;
}

__global__ void scan2b_k(int* __restrict__ partials, int nb) {
    __shared__ int sm[512];
    int t = threadIdx.x;
    int v = (t < nb) ? partials[t] : 0;
    sm[t] = v;
    __syncthreads();
    int acc = v;
    for (int d = 1; d < 512; d <<= 1) {
        int add = (t >= d) ? sm[t - d] : 0;
        __syncthreads();
        acc += add;
        sm[t] = acc;
        __syncthreads();
    }
    if (t < nb) partials[t] = acc - v;
}

__global__ void scan3_k(int* __restrict__ offs, const int* __restrict__ partials,
                        int* __restrict__ cursor, int N, int E) {
    int i = blockIdx.x * 512 + threadIdx.x;
    if (i < N) {
        int o = offs[i] + partials[blockIdx.x];
        offs[i] = o;
        cursor[i] = o;
    }
    if (i == 0) offs[N] = E;
}

// ---------------- dinv ----------------
__global__ void dinv_k(const int* __restrict__ deg, float* __restrict__ dinv, int N) {
    int n = blockIdx.x * blockDim.x + threadIdx.x;
    if (n < N) dinv[n] = 1.0f / sqrtf((float)deg[n] + 1.0f);
}

// ---------------- CSR fill (src grouped by dst) ----------------
__global__ void fill_k(const int* __restrict__ src, const int* __restrict__ dst,
                       int* __restrict__ cursor, int* __restrict__ csr, int E) {
    int e = blockIdx.x * blockDim.x + threadIdx.x;
    if (e >= E) return;
    int d = dst[e];
    int p = atomicAdd(&cursor[d], 1);
    csr[p] = src[e];
}

// ---------------- pure gather-aggregate: g[n] = dinv[n]*sum(dinv[s]*h[s]) + dinv[n]^2*h[n] ----------------
// No LDS, no barriers. 1 thread per (node, float4 lane), 2-way edge ILP.
template <int K>
__global__ __launch_bounds__(256) void agg_k(
    const float* __restrict__ h, const int* __restrict__ offs, const int* __restrict__ csr,
    const float* __restrict__ dinv, float* __restrict__ g, int N)
{
    constexpr int GA = K / 4;
    int idx = blockIdx.x * 256 + threadIdx.x;
    int node = idx / GA;
    int lane = idx % GA;
    if (node >= N) return;
    const float4* __restrict__ h4 = (const float4*)h;
    int beg = offs[node], end = offs[node + 1];
    float4 a0 = {0.f, 0.f, 0.f, 0.f}, a1 = {0.f, 0.f, 0.f, 0.f};
    int j = beg;
    for (; j + 1 < end; j += 2) {
        int s0 = csr[j], s1 = csr[j + 1];
        float w0 = dinv[s0], w1 = dinv[s1];
        float4 v0 = h4[s0 * GA + lane];
        float4 v1 = h4[s1 * GA + lane];
        a0.x = fmaf(w0, v0.x, a0.x); a0.y = fmaf(w0, v0.y, a0.y);
        a0.z = fmaf(w0, v0.z, a0.z); a0.w = fmaf(w0, v0.w, a0.w);
        a1.x = fmaf(w1, v1.x, a1.x); a1.y = fmaf(w1, v1.y, a1.y);
        a1.z = fmaf(w1, v1.z, a1.z); a1.w = fmaf(w1, v1.w, a1.w);
    }
    if (j < end) {
        int s = csr[j];
        float w = dinv[s];
        float4 v = h4[s * GA + lane];
        a0.x = fmaf(w, v.x, a0.x); a0.y = fmaf(w, v.y, a0.y);
        a0.z = fmaf(w, v.z, a0.z); a0.w = fmaf(w, v.w, a0.w);
    }
    float dn = dinv[node], dn2 = dn * dn;
    float4 hs = h4[node * GA + lane];
    float4 o;
    o.x = fmaf(dn, a0.x + a1.x, dn2 * hs.x);
    o.y = fmaf(dn, a0.y + a1.y, dn2 * hs.y);
    o.z = fmaf(dn, a0.z + a1.z, dn2 * hs.z);
    o.w = fmaf(dn, a0.w + a1.w, dn2 * hs.w);
    ((float4*)g)[node * GA + lane] = o;
}

// ---------------- streaming gemm: out = [relu](g @ W + b) [then @ W4 if FUSE4] ----------------
// Persistent grid-stride; W/bias (+W4) staged in LDS once; node rows read from global.
template <int K, int OUT, bool RELU, bool FUSE4>
__global__ __launch_bounds__(256) void gemm_k(
    const float* __restrict__ g, const float* __restrict__ W, const float* __restrict__ bias,
    const float* __restrict__ W4, float* __restrict__ out, int N, int ntiles)
{
    constexpr int JG   = OUT / 4;    // threads per node (4 outputs each)
    constexpr int NTHN = 256 / JG;   // nodes per pass
    constexpr int NPB  = NTHN * 2;   // nodes per tile (2 per thread)
    constexpr int ISTR = 132;        // padded 128 row stride for inter

    __shared__ float Wl[K * OUT];
    __shared__ float bl[OUT];
    __shared__ float W4l[FUSE4 ? 1280 : 1];
    __shared__ float inter[FUSE4 ? NPB * ISTR : 1];

    const int tid = threadIdx.x;
    for (int i = tid; i < K * OUT; i += 256) Wl[i] = W[i];
    for (int i = tid; i < OUT; i += 256) bl[i] = bias[i];
    if constexpr (FUSE4)
        for (int i = tid; i < 1280; i += 256) W4l[i] = W4[i];
    __syncthreads();

    const int jg  = tid % JG;
    const int bnl = tid / JG;
    const float4 bfrag = *(const float4*)&bl[jg * 4];

    for (int tile = blockIdx.x; tile < ntiles; tile += gridDim.x) {
        const int base = tile * NPB;
        int n0 = base + bnl, n1 = base + bnl + NTHN;
        int n0c = n0 < N ? n0 : N - 1;
        int n1c = n1 < N ? n1 : N - 1;
        const float* r0 = g + (size_t)n0c * K;
        const float* r1 = g + (size_t)n1c * K;
        float4 a0 = bfrag, a1 = bfrag;
#pragma unroll
        for (int k = 0; k < K; k += 4) {
            float4 x0 = *(const float4*)&r0[k];
            float4 x1 = *(const float4*)&r1[k];
            float4 w0 = *(const float4*)&Wl[(k + 0) * OUT + jg * 4];
            float4 w1 = *(const float4*)&Wl[(k + 1) * OUT + jg * 4];
            float4 w2 = *(const float4*)&Wl[(k + 2) * OUT + jg * 4];
            float4 w3 = *(const float4*)&Wl[(k + 3) * OUT + jg * 4];
            a0.x = fmaf(x0.x, w0.x, a0.x); a0.y = fmaf(x0.x, w0.y, a0.y);
            a0.z = fmaf(x0.x, w0.z, a0.z); a0.w = fmaf(x0.x, w0.w, a0.w);
            a0.x = fmaf(x0.y, w1.x, a0.x); a0.y = fmaf(x0.y, w1.y, a0.y);
            a0.z = fmaf(x0.y, w1.z, a0.z); a0.w = fmaf(x0.y, w1.w, a0.w);
            a0.x = fmaf(x0.z, w2.x, a0.x); a0.y = fmaf(x0.z, w2.y, a0.y);
            a0.z = fmaf(x0.z, w2.z, a0.z); a0.w = fmaf(x0.z, w2.w, a0.w);
            a0.x = fmaf(x0.w, w3.x, a0.x); a0.y = fmaf(x0.w, w3.y, a0.y);
            a0.z = fmaf(x0.w, w3.z, a0.z); a0.w = fmaf(x0.w, w3.w, a0.w);
            a1.x = fmaf(x1.x, w0.x, a1.x); a1.y = fmaf(x1.x, w0.y, a1.y);
            a1.z = fmaf(x1.x, w0.z, a1.z); a1.w = fmaf(x1.x, w0.w, a1.w);
            a1.x = fmaf(x1.y, w1.x, a1.x); a1.y = fmaf(x1.y, w1.y, a1.y);
            a1.z = fmaf(x1.y, w1.z, a1.z); a1.w = fmaf(x1.y, w1.w, a1.w);
            a1.x = fmaf(x1.z, w2.x, a1.x); a1.y = fmaf(x1.z, w2.y, a1.y);
            a1.z = fmaf(x1.z, w2.z, a1.z); a1.w = fmaf(x1.z, w2.w, a1.w);
            a1.x = fmaf(x1.w, w3.x, a1.x); a1.y = fmaf(x1.w, w3.y, a1.y);
            a1.z = fmaf(x1.w, w3.z, a1.z); a1.w = fmaf(x1.w, w3.w, a1.w);
        }
        if (RELU) {
            a0.x = fmaxf(a0.x, 0.f); a0.y = fmaxf(a0.y, 0.f);
            a0.z = fmaxf(a0.z, 0.f); a0.w = fmaxf(a0.w, 0.f);
            a1.x = fmaxf(a1.x, 0.f); a1.y = fmaxf(a1.y, 0.f);
            a1.z = fmaxf(a1.z, 0.f); a1.w = fmaxf(a1.w, 0.f);
        }
        if constexpr (!FUSE4) {
            if (n0 < N) *(float4*)&out[(size_t)n0 * OUT + jg * 4] = a0;
            if (n1 < N) *(float4*)&out[(size_t)n1 * OUT + jg * 4] = a1;
        } else {
            *(float4*)&inter[bnl * ISTR + jg * 4] = a0;
            *(float4*)&inter[(bnl + NTHN) * ISTR + jg * 4] = a1;
            __syncthreads();
            // phase C: t = inter @ W4 (128 -> 10)
            int nl = tid >> 4, j = tid & 15;
            int gn = base + nl;
            if (j < 10 && gn < N) {
                const float* iv = &inter[nl * ISTR];
                float acc = 0.f;
#pragma unroll
                for (int k = 0; k < 128; k += 4) {
                    float4 v = *(const float4*)&iv[k];
                    acc = fmaf(v.x, W4l[(k + 0) * 10 + j], acc);
                    acc = fmaf(v.y, W4l[(k + 1) * 10 + j], acc);
                    acc = fmaf(v.z, W4l[(k + 2) * 10 + j], acc);
                    acc = fmaf(v.w, W4l[(k + 3) * 10 + j], acc);
                }
                out[(size_t)gn * 10 + j] = acc;
            }
            __syncthreads();
        }
    }
}

// ---------------- fused agg(10) + bias + per-graph mean pool partials ----------------
// 10 threads per node (25 nodes per 256-thread block), 2-way edge ILP.
__global__ __launch_bounds__(256) void aggpool_k(
    const float* __restrict__ t, const int* __restrict__ offs, const int* __restrict__ csr,
    const float* __restrict__ dinv, const float* __restrict__ b4, const int* __restrict__ batch,
    float* __restrict__ pool, int N)
{
    __shared__ float lp[NGRAPH * 11];
    int tid = threadIdx.x;
    for (int i = tid; i < NGRAPH * 11; i += 256) lp[i] = 0.f;
    __syncthreads();
    int nl = tid / 10;
    int j = tid - nl * 10;
    int g = blockIdx.x * 25 + nl;
    if (nl < 25 && g < N) {
        int beg = offs[g], end = offs[g + 1];
        float acc0 = 0.f, acc1 = 0.f;
        int e = beg;
        for (; e + 1 < end; e += 2) {
            int s0 = csr[e], s1 = csr[e + 1];
            acc0 = fmaf(dinv[s0], t[s0 * 10 + j], acc0);
            acc1 = fmaf(dinv[s1], t[s1 * 10 + j], acc1);
        }
        if (e < end) {
            int s = csr[e];
            acc0 = fmaf(dinv[s], t[s * 10 + j], acc0);
        }
        float dn = dinv[g];
        float v = fmaf(dn, acc0 + acc1, dn * dn * t[g * 10 + j]) + b4[j];
        int gr = batch[g];
        atomicAdd(&lp[gr * 11 + j], v);
        if (j == 0) atomicAdd(&lp[gr * 11 + 10], 1.f);
    }
    __syncthreads();
    for (int i = tid; i < NGRAPH * 11; i += 256) {
        float v = lp[i];
        if (v != 0.f) atomicAdd(&pool[i], v);
    }
}

// ---------------- final divide ----------------
__global__ void final_k(const float* __restrict__ pool, float* __restrict__ out) {
    int i = blockIdx.x * blockDim.x + threadIdx.x;
    if (i >= NGRAPH * 10) return;
    int g = i / 10, f = i % 10;
    float c = pool[g * 11 + 10];
    out[i] = pool[g * 11 + f] / fmaxf(c, 1.f);
}

extern "C" void kernel_launch(void* const* d_in, const int* in_sizes, int n_in,
                              void* d_out, int out_size, void* d_ws, size_t ws_size,
                              hipStream_t stream) {
    const float* x   = (const float*)d_in[0];
    const float* pos = (const float*)d_in[1];
    const int* eidx  = (const int*)d_in[2];
    const int* batch = (const int*)d_in[3];
    const float* W1 = (const float*)d_in[4];  const float* b1 = (const float*)d_in[5];
    const float* W2 = (const float*)d_in[6];  const float* b2 = (const float*)d_in[7];
    const float* W3 = (const float*)d_in[8];  const float* b3 = (const float*)d_in[9];
    const float* W4 = (const float*)d_in[10]; const float* b4 = (const float*)d_in[11];

    const int N = in_sizes[0] / 8;
    const int E = in_sizes[2] / 2;
    const int* src = eidx;
    const int* dst = eidx + E;

    char* p = (char*)d_ws;
    auto alloc = [&](size_t bytes) { char* r = p; p += (bytes + 255) & ~255ull; return r; };
    int*   deg      = (int*)alloc((size_t)N * 4);
    int*   offs     = (int*)alloc((size_t)(N + 1) * 4);
    int*   cursor   = (int*)alloc((size_t)N * 4);
    int*   partials = (int*)alloc(512 * 4);
    float* dinv     = (float*)alloc((size_t)N * 4);
    int*   csr      = (int*)alloc((size_t)E * 4);
    float* bufX     = (float*)alloc((size_t)N * 64 * 4);   // aliased across layers
    float* bufY     = (float*)alloc((size_t)N * 64 * 4);
    float* bufZ     = (float*)alloc((size_t)N * 16 * 4);
    float* pool     = (float*)alloc(NGRAPH * 11 * 4);

    hipMemsetAsync(deg, 0, (size_t)N * 4, stream);
    hipMemsetAsync(pool, 0, NGRAPH * 11 * 4, stream);

    concat_k<<<(N + 255) / 256, 256, 0, stream>>>(x, pos, bufZ, N);
    deg_k<<<(E + 255) / 256, 256, 0, stream>>>(dst, deg, E);

    const int nb = (N + 511) / 512;
    scan1_k<<<nb, 512, 0, stream>>>(deg, offs, partials, N);
    scan2b_k<<<1, 512, 0, stream>>>(partials, nb);
    scan3_k<<<nb, 512, 0, stream>>>(offs, partials, cursor, N, E);
    dinv_k<<<(N + 255) / 256, 256, 0, stream>>>(deg, dinv, N);
    fill_k<<<(E + 255) / 256, 256, 0, stream>>>(src, dst, cursor, csr, E);

    auto cap = [](int t) { return t < 2048 ? t : 2048; };

    // Layer 1: agg16 (Z->X), gemm 16->32 +relu (X->Y)
    agg_k<16><<<(N * 4 + 255) / 256, 256, 0, stream>>>(bufZ, offs, csr, dinv, bufX, N);
    {
        int nt = (N + 63) / 64;
        gemm_k<16, 32, true, false><<<cap(nt), 256, 0, stream>>>(bufX, W1, b1, nullptr, bufY, N, nt);
    }
    // Layer 2: agg32 (Y->X), gemm 32->64 +relu (X->Y)
    agg_k<32><<<(N * 8 + 255) / 256, 256, 0, stream>>>(bufY, offs, csr, dinv, bufX, N);
    {
        int nt = (N + 31) / 32;
        gemm_k<32, 64, true, false><<<cap(nt), 256, 0, stream>>>(bufX, W2, b2, nullptr, bufY, N, nt);
    }
    // Layer 3+4a: agg64 (Y->X), gemm 64->128 +relu, fused @W4 -> 10 (X->Z)
    agg_k<64><<<(N * 16 + 255) / 256, 256, 0, stream>>>(bufY, offs, csr, dinv, bufX, N);
    {
        int nt = (N + 15) / 16;
        gemm_k<64, 128, true, true><<<cap(nt), 256, 0, stream>>>(bufX, W3, b3, W4, bufZ, N, nt);
    }
    // Layer 4b: agg10 + b4 + pool partials (Z -> pool)
    aggpool_k<<<(N + 24) / 25, 256, 0, stream>>>(bufZ, offs, csr, dinv, b4, batch, pool, N);
    final_k<<<3, 256, 0, stream>>>(pool, (float*)d_out);
}

// Round 10
// 431.968 us; speedup vs baseline: 2.1047x; 1.2397x over previous
//
#include <hip/hip_runtime.h>

constexpr int NGRAPH = 64;

// ---------------- concat x||pos -> h0 [N,16] ----------------
__global__ void concat_k(const float* __restrict__ x, const float* __restrict__ pos,
                         float* __restrict__ h0, int N) {
    int n = blockIdx.x * blockDim.x + threadIdx.x;
    if (n >= N) return;
    const float4* x4 = (const float4*)(x + (size_t)n * 8);
    const float4* p4 = (const float4*)(pos + (size_t)n * 8);
    float4* o4 = (float4*)(h0 + (size_t)n * 16);
    o4[0] = x4[0]; o4[1] = x4[1]; o4[2] = p4[0]; o4[3] = p4[1];
}

// ---------------- degree count ----------------
__global__ void deg_k(const int* __restrict__ dst, int* __restrict__ deg, int E) {
    int e = blockIdx.x * blockDim.x + threadIdx.x;
    if (e < E) atomicAdd(&deg[dst[e]], 1);
}

// ---------------- scan: block-local exclusive + block totals ----------------
__global__ void scan1_k(const int* __restrict__ deg, int* __restrict__ offs,
                        int* __restrict__ partials, int N) {
    __shared__ int sm[512];
    int t = threadIdx.x;
    int i = blockIdx.x * 512 + t;
    int v = (i < N) ? deg[i] : 0;
    sm[t] = v;
    __syncthreads();
    int acc = v;
    for (int d = 1; d < 512; d <<= 1) {
        int add = (t >= d) ? sm[t - d] : 0;
        __syncthreads();
        acc += add;
        sm[t] = acc;
        __syncthreads();
    }
    if (i < N) offs[i] = acc - v;
    if (t == 511) partials[blockIdx.x] = acc;
}

__global__ void scan2b_k(int* __restrict__ partials, int nb) {
    __shared__ int sm[512];
    int t = threadIdx.x;
    int v = (t < nb) ? partials[t] : 0;
    sm[t] = v;
    __syncthreads();
    int acc = v;
    for (int d = 1; d < 512; d <<= 1) {
        int add = (t >= d) ? sm[t - d] : 0;
        __syncthreads();
        acc += add;
        sm[t] = acc;
        __syncthreads();
    }
    if (t < nb) partials[t] = acc - v;
}

__global__ void scan3_k(int* __restrict__ offs, const int* __restrict__ partials,
                        int* __restrict__ cursor, int N, int E) {
    int i = blockIdx.x * 512 + threadIdx.x;
    if (i < N) {
        int o = offs[i] + partials[blockIdx.x];
        offs[i] = o;
        cursor[i] = o;
    }
    if (i == 0) offs[N] = E;
}

// ---------------- dinv ----------------
__global__ void dinv_k(const int* __restrict__ deg, float* __restrict__ dinv, int N) {
    int n = blockIdx.x * blockDim.x + threadIdx.x;
    if (n < N) dinv[n] = 1.0f / sqrtf((float)deg[n] + 1.0f);
}

// ---------------- bucket cursor init: bcur[b] = offs[b << shift] ----------------
__global__ void binit_k(const int* __restrict__ offs, int* __restrict__ bcur,
                        int nbuckets, int shift, int N) {
    int t = threadIdx.x;
    if (t < 256) {
        int node = t << shift;
        bcur[t] = (t < nbuckets && node < N) ? offs[node] : 0;
    }
}

// ---------------- bucket scatter: block-local counting sort of a 4096-edge chunk ----------------
__global__ __launch_bounds__(256) void scatter_k(
    const int* __restrict__ src, const int* __restrict__ dst,
    int* __restrict__ bcur, uint2* __restrict__ bucketed, int E, int shift)
{
    constexpr int CHUNK = 4096, EPT = 16;
    __shared__ uint2 recs[CHUNK];
    __shared__ int hist[256], sm[256], hoff[256], wcur[256], gbase[256];
    const int tid = threadIdx.x;
    const int base = blockIdx.x * CHUNK;
    int es[EPT], ed[EPT];
    hist[tid] = 0;
    __syncthreads();
#pragma unroll
    for (int k = 0; k < EPT; ++k) {
        int e = base + tid + k * 256;
        if (e < E) { es[k] = src[e]; ed[k] = dst[e]; }
        else       { ed[k] = -1; es[k] = 0; }
    }
#pragma unroll
    for (int k = 0; k < EPT; ++k)
        if (ed[k] >= 0) atomicAdd(&hist[ed[k] >> shift], 1);
    __syncthreads();
    int v = hist[tid];
    sm[tid] = v;
    __syncthreads();
    int acc = v;
    for (int d = 1; d < 256; d <<= 1) {
        int add = (tid >= d) ? sm[tid - d] : 0;
        __syncthreads();
        acc += add;
        sm[tid] = acc;
        __syncthreads();
    }
    hoff[tid] = acc - v;
    wcur[tid] = acc - v;
    __syncthreads();
#pragma unroll
    for (int k = 0; k < EPT; ++k) {
        if (ed[k] >= 0) {
            int b = ed[k] >> shift;
            int p = atomicAdd(&wcur[b], 1);
            recs[p] = make_uint2((unsigned)es[k], (unsigned)ed[k]);
        }
    }
    __syncthreads();
    int cnt = hist[tid];
    if (cnt > 0) gbase[tid] = atomicAdd(&bcur[tid], cnt);
    __syncthreads();
    const int VC = min(CHUNK, E - base);
    for (int i = tid; i < VC; i += 256) {
        uint2 r = recs[i];
        int b = (int)(r.y >> shift);
        bucketed[gbase[b] + (i - hoff[b])] = r;
    }
}

// ---------------- bucket fill: one block per bucket, csr window built in LDS ----------------
__global__ __launch_bounds__(256) void bfill_k(
    const uint2* __restrict__ bucketed, const int* __restrict__ offs,
    int* __restrict__ gcur, int* __restrict__ csr, int N, int shift)
{
    __shared__ int lcsr[16384];
    __shared__ int lcur[512];
    const int b = blockIdx.x;
    const int node_lo = b << shift;
    const int node_hi = min(node_lo + (1 << shift), N);
    const int wbase = offs[node_lo];
    const int wend  = offs[node_hi];
    const int wsize = wend - wbase;
    const int range = node_hi - node_lo;
    const int tid = threadIdx.x;
    if (wsize <= 16384 && range <= 512) {
        for (int i = tid; i < range; i += 256)
            lcur[i] = offs[node_lo + i] - wbase;
        __syncthreads();
        for (int i = wbase + tid; i < wend; i += 256) {
            uint2 r = bucketed[i];
            int p = atomicAdd(&lcur[(int)r.y - node_lo], 1);
            lcsr[p] = (int)r.x;
        }
        __syncthreads();
        for (int i = tid; i < wsize; i += 256)
            csr[wbase + i] = lcsr[i];
    } else {
        for (int i = wbase + tid; i < wend; i += 256) {
            uint2 r = bucketed[i];
            int p = atomicAdd(&gcur[(int)r.y], 1);
            csr[p] = (int)r.x;
        }
    }
}

// ---------------- pure gather-aggregate ----------------
template <int K>
__global__ __launch_bounds__(256) void agg_k(
    const float* __restrict__ h, const int* __restrict__ offs, const int* __restrict__ csr,
    const float* __restrict__ dinv, float* __restrict__ g, int N)
{
    constexpr int GA = K / 4;
    int idx = blockIdx.x * 256 + threadIdx.x;
    int node = idx / GA;
    int lane = idx % GA;
    if (node >= N) return;
    const float4* __restrict__ h4 = (const float4*)h;
    int beg = offs[node], end = offs[node + 1];
    float4 a0 = {0.f, 0.f, 0.f, 0.f}, a1 = {0.f, 0.f, 0.f, 0.f};
    int j = beg;
    for (; j + 1 < end; j += 2) {
        int s0 = csr[j], s1 = csr[j + 1];
        float w0 = dinv[s0], w1 = dinv[s1];
        float4 v0 = h4[s0 * GA + lane];
        float4 v1 = h4[s1 * GA + lane];
        a0.x = fmaf(w0, v0.x, a0.x); a0.y = fmaf(w0, v0.y, a0.y);
        a0.z = fmaf(w0, v0.z, a0.z); a0.w = fmaf(w0, v0.w, a0.w);
        a1.x = fmaf(w1, v1.x, a1.x); a1.y = fmaf(w1, v1.y, a1.y);
        a1.z = fmaf(w1, v1.z, a1.z); a1.w = fmaf(w1, v1.w, a1.w);
    }
    if (j < end) {
        int s = csr[j];
        float w = dinv[s];
        float4 v = h4[s * GA + lane];
        a0.x = fmaf(w, v.x, a0.x); a0.y = fmaf(w, v.y, a0.y);
        a0.z = fmaf(w, v.z, a0.z); a0.w = fmaf(w, v.w, a0.w);
    }
    float dn = dinv[node], dn2 = dn * dn;
    float4 hs = h4[node * GA + lane];
    float4 o;
    o.x = fmaf(dn, a0.x + a1.x, dn2 * hs.x);
    o.y = fmaf(dn, a0.y + a1.y, dn2 * hs.y);
    o.z = fmaf(dn, a0.z + a1.z, dn2 * hs.z);
    o.w = fmaf(dn, a0.w + a1.w, dn2 * hs.w);
    ((float4*)g)[node * GA + lane] = o;
}

// ---------------- streaming gemm: out = [relu](g @ W + b) [then @ W4 if FUSE4] ----------------
template <int K, int OUT, bool RELU, bool FUSE4>
__global__ __launch_bounds__(256) void gemm_k(
    const float* __restrict__ g, const float* __restrict__ W, const float* __restrict__ bias,
    const float* __restrict__ W4, float* __restrict__ out, int N, int ntiles)
{
    constexpr int JG   = OUT / 4;
    constexpr int NTHN = 256 / JG;
    constexpr int NPB  = NTHN * 2;
    constexpr int ISTR = 132;

    __shared__ float Wl[K * OUT];
    __shared__ float bl[OUT];
    __shared__ float W4l[FUSE4 ? 1280 : 1];
    __shared__ float inter[FUSE4 ? NPB * ISTR : 1];

    const int tid = threadIdx.x;
    for (int i = tid; i < K * OUT; i += 256) Wl[i] = W[i];
    for (int i = tid; i < OUT; i += 256) bl[i] = bias[i];
    if constexpr (FUSE4)
        for (int i = tid; i < 1280; i += 256) W4l[i] = W4[i];
    __syncthreads();

    const int jg  = tid % JG;
    const int bnl = tid / JG;
    const float4 bfrag = *(const float4*)&bl[jg * 4];

    for (int tile = blockIdx.x; tile < ntiles; tile += gridDim.x) {
        const int base = tile * NPB;
        int n0 = base + bnl, n1 = base + bnl + NTHN;
        int n0c = n0 < N ? n0 : N - 1;
        int n1c = n1 < N ? n1 : N - 1;
        const float* r0 = g + (size_t)n0c * K;
        const float* r1 = g + (size_t)n1c * K;
        float4 a0 = bfrag, a1 = bfrag;
#pragma unroll
        for (int k = 0; k < K; k += 4) {
            float4 x0 = *(const float4*)&r0[k];
            float4 x1 = *(const float4*)&r1[k];
            float4 w0 = *(const float4*)&Wl[(k + 0) * OUT + jg * 4];
            float4 w1 = *(const float4*)&Wl[(k + 1) * OUT + jg * 4];
            float4 w2 = *(const float4*)&Wl[(k + 2) * OUT + jg * 4];
            float4 w3 = *(const float4*)&Wl[(k + 3) * OUT + jg * 4];
            a0.x = fmaf(x0.x, w0.x, a0.x); a0.y = fmaf(x0.x, w0.y, a0.y);
            a0.z = fmaf(x0.x, w0.z, a0.z); a0.w = fmaf(x0.x, w0.w, a0.w);
            a0.x = fmaf(x0.y, w1.x, a0.x); a0.y = fmaf(x0.y, w1.y, a0.y);
            a0.z = fmaf(x0.y, w1.z, a0.z); a0.w = fmaf(x0.y, w1.w, a0.w);
            a0.x = fmaf(x0.z, w2.x, a0.x); a0.y = fmaf(x0.z, w2.y, a0.y);
            a0.z = fmaf(x0.z, w2.z, a0.z); a0.w = fmaf(x0.z, w2.w, a0.w);
            a0.x = fmaf(x0.w, w3.x, a0.x); a0.y = fmaf(x0.w, w3.y, a0.y);
            a0.z = fmaf(x0.w, w3.z, a0.z); a0.w = fmaf(x0.w, w3.w, a0.w);
            a1.x = fmaf(x1.x, w0.x, a1.x); a1.y = fmaf(x1.x, w0.y, a1.y);
            a1.z = fmaf(x1.x, w0.z, a1.z); a1.w = fmaf(x1.x, w0.w, a1.w);
            a1.x = fmaf(x1.y, w1.x, a1.x); a1.y = fmaf(x1.y, w1.y, a1.y);
            a1.z = fmaf(x1.y, w1.z, a1.z); a1.w = fmaf(x1.y, w1.w, a1.w);
            a1.x = fmaf(x1.z, w2.x, a1.x); a1.y = fmaf(x1.z, w2.y, a1.y);
            a1.z = fmaf(x1.z, w2.z, a1.z); a1.w = fmaf(x1.z, w2.w, a1.w);
            a1.x = fmaf(x1.w, w3.x, a1.x); a1.y = fmaf(x1.w, w3.y, a1.y);
            a1.z = fmaf(x1.w, w3.z, a1.z); a1.w = fmaf(x1.w, w3.w, a1.w);
        }
        if (RELU) {
            a0.x = fmaxf(a0.x, 0.f); a0.y = fmaxf(a0.y, 0.f);
            a0.z = fmaxf(a0.z, 0.f); a0.w = fmaxf(a0.w, 0.f);
            a1.x = fmaxf(a1.x, 0.f); a1.y = fmaxf(a1.y, 0.f);
            a1.z = fmaxf(a1.z, 0.f); a1.w = fmaxf(a1.w, 0.f);
        }
        if constexpr (!FUSE4) {
            if (n0 < N) *(float4*)&out[(size_t)n0 * OUT + jg * 4] = a0;
            if (n1 < N) *(float4*)&out[(size_t)n1 * OUT + jg * 4] = a1;
        } else {
            *(float4*)&inter[bnl * ISTR + jg * 4] = a0;
            *(float4*)&inter[(bnl + NTHN) * ISTR + jg * 4] = a1;
            __syncthreads();
            int nl = tid >> 4, j = tid & 15;
            int gn = base + nl;
            if (j < 10 && gn < N) {
                const float* iv = &inter[nl * ISTR];
                float acc = 0.f;
#pragma unroll
                for (int k = 0; k < 128; k += 4) {
                    float4 v = *(const float4*)&iv[k];
                    acc = fmaf(v.x, W4l[(k + 0) * 10 + j], acc);
                    acc = fmaf(v.y, W4l[(k + 1) * 10 + j], acc);
                    acc = fmaf(v.z, W4l[(k + 2) * 10 + j], acc);
                    acc = fmaf(v.w, W4l[(k + 3) * 10 + j], acc);
                }
                out[(size_t)gn * 10 + j] = acc;
            }
            __syncthreads();
        }
    }
}

// ---------------- fused agg(10) + bias + per-graph mean pool partials ----------------
__global__ __launch_bounds__(256) void aggpool_k(
    const float* __restrict__ t, const int* __restrict__ offs, const int* __restrict__ csr,
    const float* __restrict__ dinv, const float* __restrict__ b4, const int* __restrict__ batch,
    float* __restrict__ pool, int N)
{
    __shared__ float lp[NGRAPH * 11];
    int tid = threadIdx.x;
    for (int i = tid; i < NGRAPH * 11; i += 256) lp[i] = 0.f;
    __syncthreads();
    int nl = tid / 10;
    int j = tid - nl * 10;
    int g = blockIdx.x * 25 + nl;
    if (nl < 25 && g < N) {
        int beg = offs[g], end = offs[g + 1];
        float acc0 = 0.f, acc1 = 0.f;
        int e = beg;
        for (; e + 1 < end; e += 2) {
            int s0 = csr[e], s1 = csr[e + 1];
            acc0 = fmaf(dinv[s0], t[s0 * 10 + j], acc0);
            acc1 = fmaf(dinv[s1], t[s1 * 10 + j], acc1);
        }
        if (e < end) {
            int s = csr[e];
            acc0 = fmaf(dinv[s], t[s * 10 + j], acc0);
        }
        float dn = dinv[g];
        float v = fmaf(dn, acc0 + acc1, dn * dn * t[g * 10 + j]) + b4[j];
        int gr = batch[g];
        atomicAdd(&lp[gr * 11 + j], v);
        if (j == 0) atomicAdd(&lp[gr * 11 + 10], 1.f);
    }
    __syncthreads();
    for (int i = tid; i < NGRAPH * 11; i += 256) {
        float v = lp[i];
        if (v != 0.f) atomicAdd(&pool[i], v);
    }
}

// ---------------- final divide ----------------
__global__ void final_k(const float* __restrict__ pool, float* __restrict__ out) {
    int i = blockIdx.x * blockDim.x + threadIdx.x;
    if (i >= NGRAPH * 10) return;
    int g = i / 10, f = i % 10;
    float c = pool[g * 11 + 10];
    out[i] = pool[g * 11 + f] / fmaxf(c, 1.f);
}

extern "C" void kernel_launch(void* const* d_in, const int* in_sizes, int n_in,
                              void* d_out, int out_size, void* d_ws, size_t ws_size,
                              hipStream_t stream) {
    const float* x   = (const float*)d_in[0];
    const float* pos = (const float*)d_in[1];
    const int* eidx  = (const int*)d_in[2];
    const int* batch = (const int*)d_in[3];
    const float* W1 = (const float*)d_in[4];  const float* b1 = (const float*)d_in[5];
    const float* W2 = (const float*)d_in[6];  const float* b2 = (const float*)d_in[7];
    const float* W3 = (const float*)d_in[8];  const float* b3 = (const float*)d_in[9];
    const float* W4 = (const float*)d_in[10]; const float* b4 = (const float*)d_in[11];

    const int N = in_sizes[0] / 8;
    const int E = in_sizes[2] / 2;
    const int* src = eidx;
    const int* dst = eidx + E;

    char* p = (char*)d_ws;
    auto alloc = [&](size_t bytes) { char* r = p; p += (bytes + 255) & ~255ull; return r; };
    int*   deg      = (int*)alloc((size_t)N * 4);
    int*   offs     = (int*)alloc((size_t)(N + 1) * 4);
    int*   cursor   = (int*)alloc((size_t)N * 4);
    int*   partials = (int*)alloc(512 * 4);
    int*   bcur     = (int*)alloc(256 * 4);
    float* dinv     = (float*)alloc((size_t)N * 4);
    int*   csr      = (int*)alloc((size_t)E * 4);
    uint2* bucketed = (uint2*)alloc((size_t)E * 8);
    float* bufX     = (float*)alloc((size_t)N * 64 * 4);
    float* bufY     = (float*)alloc((size_t)N * 64 * 4);
    float* bufZ     = (float*)alloc((size_t)N * 16 * 4);
    float* pool     = (float*)alloc(NGRAPH * 11 * 4);

    hipMemsetAsync(deg, 0, (size_t)N * 4, stream);
    hipMemsetAsync(pool, 0, NGRAPH * 11 * 4, stream);

    concat_k<<<(N + 255) / 256, 256, 0, stream>>>(x, pos, bufZ, N);
    deg_k<<<(E + 255) / 256, 256, 0, stream>>>(dst, deg, E);

    const int nb = (N + 511) / 512;
    scan1_k<<<nb, 512, 0, stream>>>(deg, offs, partials, N);
    scan2b_k<<<1, 512, 0, stream>>>(partials, nb);
    scan3_k<<<nb, 512, 0, stream>>>(offs, partials, cursor, N, E);
    dinv_k<<<(N + 255) / 256, 256, 0, stream>>>(deg, dinv, N);

    // bucketed CSR build (locality-structured: bucket = dst >> shift, aligned with offs)
    int shift = 9;
    while ((((N + (1 << shift) - 1) >> shift)) > 256) ++shift;
    const int nbuckets = (N + (1 << shift) - 1) >> shift;
    binit_k<<<1, 256, 0, stream>>>(offs, bcur, nbuckets, shift, N);
    scatter_k<<<(E + 4095) / 4096, 256, 0, stream>>>(src, dst, bcur, bucketed, E, shift);
    bfill_k<<<nbuckets, 256, 0, stream>>>(bucketed, offs, cursor, csr, N, shift);

    auto cap = [](int t) { return t < 2048 ? t : 2048; };

    // Layer 1: agg16 (Z->X), gemm 16->32 +relu (X->Y)
    agg_k<16><<<(N * 4 + 255) / 256, 256, 0, stream>>>(bufZ, offs, csr, dinv, bufX, N);
    {
        int nt = (N + 63) / 64;
        gemm_k<16, 32, true, false><<<cap(nt), 256, 0, stream>>>(bufX, W1, b1, nullptr, bufY, N, nt);
    }
    // Layer 2: agg32 (Y->X), gemm 32->64 +relu (X->Y)
    agg_k<32><<<(N * 8 + 255) / 256, 256, 0, stream>>>(bufY, offs, csr, dinv, bufX, N);
    {
        int nt = (N + 31) / 32;
        gemm_k<32, 64, true, false><<<cap(nt), 256, 0, stream>>>(bufX, W2, b2, nullptr, bufY, N, nt);
    }
    // Layer 3+4a: agg64 (Y->X), gemm 64->128 +relu, fused @W4 -> 10 (X->Z)
    agg_k<64><<<(N * 16 + 255) / 256, 256, 0, stream>>>(bufY, offs, csr, dinv, bufX, N);
    {
        int nt = (N + 15) / 16;
        gemm_k<64, 128, true, true><<<cap(nt), 256, 0, stream>>>(bufX, W3, b3, W4, bufZ, N, nt);
    }
    // Layer 4b: agg10 + b4 + pool partials (Z -> pool)
    aggpool_k<<<(N + 24) / 25, 256, 0, stream>>>(bufZ, offs, csr, dinv, b4, batch, pool, N);
    final_k<<<3, 256, 0, stream>>>(pool, (float*)d_out);
}

// Round 12
// 368.369 us; speedup vs baseline: 2.4681x; 1.1726x over previous
//
#include <hip/hip_runtime.h>

constexpr int NGRAPH = 64;

// ---------------- concat x||pos -> h0 [N,16] ----------------
__global__ void concat_k(const float* __restrict__ x, const float* __restrict__ pos,
                         float* __restrict__ h0, int N) {
    int n = blockIdx.x * blockDim.x + threadIdx.x;
    if (n >= N) return;
    const float4* x4 = (const float4*)(x + (size_t)n * 8);
    const float4* p4 = (const float4*)(pos + (size_t)n * 8);
    float4* o4 = (float4*)(h0 + (size_t)n * 16);
    o4[0] = x4[0]; o4[1] = x4[1]; o4[2] = p4[0]; o4[3] = p4[1];
}

// ---------------- scan: block-local exclusive + block totals ----------------
__global__ void scan1_k(const int* __restrict__ deg, int* __restrict__ offs,
                        int* __restrict__ partials, int N) {
    __shared__ int sm[512];
    int t = threadIdx.x;
    int i = blockIdx.x * 512 + t;
    int v = (i < N) ? deg[i] : 0;
    sm[t] = v;
    __syncthreads();
    int acc = v;
    for (int d = 1; d < 512; d <<= 1) {
        int add = (t >= d) ? sm[t - d] : 0;
        __syncthreads();
        acc += add;
        sm[t] = acc;
        __syncthreads();
    }
    if (i < N) offs[i] = acc - v;
    if (t == 511) partials[blockIdx.x] = acc;
}

__global__ void scan2b_k(int* __restrict__ partials, int nb) {
    __shared__ int sm[512];
    int t = threadIdx.x;
    int v = (t < nb) ? partials[t] : 0;
    sm[t] = v;
    __syncthreads();
    int acc = v;
    for (int d = 1; d < 512; d <<= 1) {
        int add = (t >= d) ? sm[t - d] : 0;
        __syncthreads();
        acc += add;
        sm[t] = acc;
        __syncthreads();
    }
    if (t < nb) partials[t] = acc - v;
}

__global__ void scan3_k(int* __restrict__ offs, const int* __restrict__ partials,
                        int* __restrict__ cursor, int N, int E) {
    int i = blockIdx.x * 512 + threadIdx.x;
    if (i < N) {
        int o = offs[i] + partials[blockIdx.x];
        offs[i] = o;
        cursor[i] = o;
    }
    if (i == 0) offs[N] = E;
}

// ---------------- dinv ----------------
__global__ void dinv_k(const int* __restrict__ deg, float* __restrict__ dinv, int N) {
    int n = blockIdx.x * blockDim.x + threadIdx.x;
    if (n < N) dinv[n] = 1.0f / sqrtf((float)deg[n] + 1.0f);
}

// ---------------- bucket cursor init: bcur[b] = b * capB (fixed-capacity regions) ----------------
__global__ void binit_k(int* __restrict__ bcur, int nbuckets, int capB) {
    int t = threadIdx.x;
    if (t < 256) bcur[t] = (t < nbuckets) ? t * capB : 0;
}

// ---------------- bucket scatter: block-local counting sort of a 4096-edge chunk ----------------
__global__ __launch_bounds__(256) void scatter_k(
    const int* __restrict__ src, const int* __restrict__ dst,
    int* __restrict__ bcur, uint2* __restrict__ bucketed, int E, int shift)
{
    constexpr int CHUNK = 4096, EPT = 16;
    __shared__ uint2 recs[CHUNK];
    __shared__ int hist[256], sm[256], hoff[256], wcur[256], gbase[256];
    const int tid = threadIdx.x;
    const int base = blockIdx.x * CHUNK;
    int es[EPT], ed[EPT];
    hist[tid] = 0;
    __syncthreads();
#pragma unroll
    for (int k = 0; k < EPT; ++k) {
        int e = base + tid + k * 256;
        if (e < E) { es[k] = src[e]; ed[k] = dst[e]; }
        else       { ed[k] = -1; es[k] = 0; }
    }
#pragma unroll
    for (int k = 0; k < EPT; ++k)
        if (ed[k] >= 0) atomicAdd(&hist[ed[k] >> shift], 1);
    __syncthreads();
    int v = hist[tid];
    sm[tid] = v;
    __syncthreads();
    int acc = v;
    for (int d = 1; d < 256; d <<= 1) {
        int add = (tid >= d) ? sm[tid - d] : 0;
        __syncthreads();
        acc += add;
        sm[tid] = acc;
        __syncthreads();
    }
    hoff[tid] = acc - v;
    wcur[tid] = acc - v;
    __syncthreads();
#pragma unroll
    for (int k = 0; k < EPT; ++k) {
        if (ed[k] >= 0) {
            int b = ed[k] >> shift;
            int p = atomicAdd(&wcur[b], 1);
            recs[p] = make_uint2((unsigned)es[k], (unsigned)ed[k]);
        }
    }
    __syncthreads();
    int cnt = hist[tid];
    if (cnt > 0) gbase[tid] = atomicAdd(&bcur[tid], cnt);
    __syncthreads();
    const int VC = min(CHUNK, E - base);
    for (int i = tid; i < VC; i += 256) {
        uint2 r = recs[i];
        int b = (int)(r.y >> shift);
        bucketed[gbase[b] + (i - hoff[b])] = r;
    }
}

// ---------------- bucket degree count: LDS counters, coalesced deg write ----------------
__global__ __launch_bounds__(256) void bdeg_k(
    const uint2* __restrict__ bucketed, const int* __restrict__ bcur,
    int* __restrict__ deg, int capB, int N, int shift)
{
    __shared__ int lcnt[512];
    const int b = blockIdx.x;
    const int node_lo = b << shift;
    const int node_hi = min(node_lo + (1 << shift), N);
    const int range = node_hi - node_lo;
    const int tid = threadIdx.x;
    for (int i = tid; i < range; i += 256) lcnt[i] = 0;
    __syncthreads();
    const int beg = b * capB;
    const int end = bcur[b];
    for (int i = beg + tid; i < end; i += 256) {
        uint2 r = bucketed[i];
        atomicAdd(&lcnt[(int)r.y - node_lo], 1);
    }
    __syncthreads();
    for (int i = tid; i < range; i += 256) deg[node_lo + i] = lcnt[i];
}

// ---------------- bucket fill: one block per bucket, csr window built in LDS ----------------
__global__ __launch_bounds__(256) void bfill_k(
    const uint2* __restrict__ bucketed, const int* __restrict__ bcur,
    const int* __restrict__ offs, int* __restrict__ gcur, int* __restrict__ csr,
    int capB, int N, int shift)
{
    __shared__ int lcsr[16384];
    __shared__ int lcur[512];
    const int b = blockIdx.x;
    const int node_lo = b << shift;
    const int node_hi = min(node_lo + (1 << shift), N);
    const int wbase = offs[node_lo];
    const int wend  = offs[node_hi];
    const int wsize = wend - wbase;
    const int range = node_hi - node_lo;
    const int beg = b * capB;
    const int end = bcur[b];
    const int tid = threadIdx.x;
    if (wsize <= 16384 && range <= 512) {
        for (int i = tid; i < range; i += 256)
            lcur[i] = offs[node_lo + i] - wbase;
        __syncthreads();
        for (int i = beg + tid; i < end; i += 256) {
            uint2 r = bucketed[i];
            int p = atomicAdd(&lcur[(int)r.y - node_lo], 1);
            lcsr[p] = (int)r.x;
        }
        __syncthreads();
        for (int i = tid; i < wsize; i += 256)
            csr[wbase + i] = lcsr[i];
    } else {
        for (int i = beg + tid; i < end; i += 256) {
            uint2 r = bucketed[i];
            int p = atomicAdd(&gcur[(int)r.y], 1);
            csr[p] = (int)r.x;
        }
    }
}

// ---------------- pure gather-aggregate ----------------
template <int K>
__global__ __launch_bounds__(256) void agg_k(
    const float* __restrict__ h, const int* __restrict__ offs, const int* __restrict__ csr,
    const float* __restrict__ dinv, float* __restrict__ g, int N)
{
    constexpr int GA = K / 4;
    int idx = blockIdx.x * 256 + threadIdx.x;
    int node = idx / GA;
    int lane = idx % GA;
    if (node >= N) return;
    const float4* __restrict__ h4 = (const float4*)h;
    int beg = offs[node], end = offs[node + 1];
    float4 a0 = {0.f, 0.f, 0.f, 0.f}, a1 = {0.f, 0.f, 0.f, 0.f};
    int j = beg;
    for (; j + 1 < end; j += 2) {
        int s0 = csr[j], s1 = csr[j + 1];
        float w0 = dinv[s0], w1 = dinv[s1];
        float4 v0 = h4[s0 * GA + lane];
        float4 v1 = h4[s1 * GA + lane];
        a0.x = fmaf(w0, v0.x, a0.x); a0.y = fmaf(w0, v0.y, a0.y);
        a0.z = fmaf(w0, v0.z, a0.z); a0.w = fmaf(w0, v0.w, a0.w);
        a1.x = fmaf(w1, v1.x, a1.x); a1.y = fmaf(w1, v1.y, a1.y);
        a1.z = fmaf(w1, v1.z, a1.z); a1.w = fmaf(w1, v1.w, a1.w);
    }
    if (j < end) {
        int s = csr[j];
        float w = dinv[s];
        float4 v = h4[s * GA + lane];
        a0.x = fmaf(w, v.x, a0.x); a0.y = fmaf(w, v.y, a0.y);
        a0.z = fmaf(w, v.z, a0.z); a0.w = fmaf(w, v.w, a0.w);
    }
    float dn = dinv[node], dn2 = dn * dn;
    float4 hs = h4[node * GA + lane];
    float4 o;
    o.x = fmaf(dn, a0.x + a1.x, dn2 * hs.x);
    o.y = fmaf(dn, a0.y + a1.y, dn2 * hs.y);
    o.z = fmaf(dn, a0.z + a1.z, dn2 * hs.z);
    o.w = fmaf(dn, a0.w + a1.w, dn2 * hs.w);
    ((float4*)g)[node * GA + lane] = o;
}

// ---------------- streaming gemm: out = [relu](g @ W + b) [then @ W4 if FUSE4] ----------------
template <int K, int OUT, bool RELU, bool FUSE4>
__global__ __launch_bounds__(256) void gemm_k(
    const float* __restrict__ g, const float* __restrict__ W, const float* __restrict__ bias,
    const float* __restrict__ W4, float* __restrict__ out, int N, int ntiles)
{
    constexpr int JG   = OUT / 4;
    constexpr int NTHN = 256 / JG;
    constexpr int NPB  = NTHN * 2;
    constexpr int ISTR = 132;

    __shared__ float Wl[K * OUT];
    __shared__ float bl[OUT];
    __shared__ float W4l[FUSE4 ? 1280 : 1];
    __shared__ float inter[FUSE4 ? NPB * ISTR : 1];

    const int tid = threadIdx.x;
    for (int i = tid; i < K * OUT; i += 256) Wl[i] = W[i];
    for (int i = tid; i < OUT; i += 256) bl[i] = bias[i];
    if constexpr (FUSE4)
        for (int i = tid; i < 1280; i += 256) W4l[i] = W4[i];
    __syncthreads();

    const int jg  = tid % JG;
    const int bnl = tid / JG;
    const float4 bfrag = *(const float4*)&bl[jg * 4];

    for (int tile = blockIdx.x; tile < ntiles; tile += gridDim.x) {
        const int base = tile * NPB;
        int n0 = base + bnl, n1 = base + bnl + NTHN;
        int n0c = n0 < N ? n0 : N - 1;
        int n1c = n1 < N ? n1 : N - 1;
        const float* r0 = g + (size_t)n0c * K;
        const float* r1 = g + (size_t)n1c * K;
        float4 a0 = bfrag, a1 = bfrag;
#pragma unroll
        for (int k = 0; k < K; k += 4) {
            float4 x0 = *(const float4*)&r0[k];
            float4 x1 = *(const float4*)&r1[k];
            float4 w0 = *(const float4*)&Wl[(k + 0) * OUT + jg * 4];
            float4 w1 = *(const float4*)&Wl[(k + 1) * OUT + jg * 4];
            float4 w2 = *(const float4*)&Wl[(k + 2) * OUT + jg * 4];
            float4 w3 = *(const float4*)&Wl[(k + 3) * OUT + jg * 4];
            a0.x = fmaf(x0.x, w0.x, a0.x); a0.y = fmaf(x0.x, w0.y, a0.y);
            a0.z = fmaf(x0.x, w0.z, a0.z); a0.w = fmaf(x0.x, w0.w, a0.w);
            a0.x = fmaf(x0.y, w1.x, a0.x); a0.y = fmaf(x0.y, w1.y, a0.y);
            a0.z = fmaf(x0.y, w1.z, a0.z); a0.w = fmaf(x0.y, w1.w, a0.w);
            a0.x = fmaf(x0.z, w2.x, a0.x); a0.y = fmaf(x0.z, w2.y, a0.y);
            a0.z = fmaf(x0.z, w2.z, a0.z); a0.w = fmaf(x0.z, w2.w, a0.w);
            a0.x = fmaf(x0.w, w3.x, a0.x); a0.y = fmaf(x0.w, w3.y, a0.y);
            a0.z = fmaf(x0.w, w3.z, a0.z); a0.w = fmaf(x0.w, w3.w, a0.w);
            a1.x = fmaf(x1.x, w0.x, a1.x); a1.y = fmaf(x1.x, w0.y, a1.y);
            a1.z = fmaf(x1.x, w0.z, a1.z); a1.w = fmaf(x1.x, w0.w, a1.w);
            a1.x = fmaf(x1.y, w1.x, a1.x); a1.y = fmaf(x1.y, w1.y, a1.y);
            a1.z = fmaf(x1.y, w1.z, a1.z); a1.w = fmaf(x1.y, w1.w, a1.w);
            a1.x = fmaf(x1.z, w2.x, a1.x); a1.y = fmaf(x1.z, w2.y, a1.y);
            a1.z = fmaf(x1.z, w2.z, a1.z); a1.w = fmaf(x1.z, w2.w, a1.w);
            a1.x = fmaf(x1.w, w3.x, a1.x); a1.y = fmaf(x1.w, w3.y, a1.y);
            a1.z = fmaf(x1.w, w3.z, a1.z); a1.w = fmaf(x1.w, w3.w, a1.w);
        }
        if (RELU) {
            a0.x = fmaxf(a0.x, 0.f); a0.y = fmaxf(a0.y, 0.f);
            a0.z = fmaxf(a0.z, 0.f); a0.w = fmaxf(a0.w, 0.f);
            a1.x = fmaxf(a1.x, 0.f); a1.y = fmaxf(a1.y, 0.f);
            a1.z = fmaxf(a1.z, 0.f); a1.w = fmaxf(a1.w, 0.f);
        }
        if constexpr (!FUSE4) {
            if (n0 < N) *(float4*)&out[(size_t)n0 * OUT + jg * 4] = a0;
            if (n1 < N) *(float4*)&out[(size_t)n1 * OUT + jg * 4] = a1;
        } else {
            *(float4*)&inter[bnl * ISTR + jg * 4] = a0;
            *(float4*)&inter[(bnl + NTHN) * ISTR + jg * 4] = a1;
            __syncthreads();
            int nl = tid >> 4, j = tid & 15;
            int gn = base + nl;
            if (j < 10 && gn < N) {
                const float* iv = &inter[nl * ISTR];
                float acc = 0.f;
#pragma unroll
                for (int k = 0; k < 128; k += 4) {
                    float4 v = *(const float4*)&iv[k];
                    acc = fmaf(v.x, W4l[(k + 0) * 10 + j], acc);
                    acc = fmaf(v.y, W4l[(k + 1) * 10 + j], acc);
                    acc = fmaf(v.z, W4l[(k + 2) * 10 + j], acc);
                    acc = fmaf(v.w, W4l[(k + 3) * 10 + j], acc);
                }
                out[(size_t)gn * 10 + j] = acc;
            }
            __syncthreads();
        }
    }
}

// ---------------- fused agg(10) + bias + per-graph mean pool partials ----------------
__global__ __launch_bounds__(256) void aggpool_k(
    const float* __restrict__ t, const int* __restrict__ offs, const int* __restrict__ csr,
    const float* __restrict__ dinv, const float* __restrict__ b4, const int* __restrict__ batch,
    float* __restrict__ pool, int N)
{
    __shared__ float lp[NGRAPH * 11];
    int tid = threadIdx.x;
    for (int i = tid; i < NGRAPH * 11; i += 256) lp[i] = 0.f;
    __syncthreads();
    int nl = tid / 10;
    int j = tid - nl * 10;
    int g = blockIdx.x * 25 + nl;
    if (nl < 25 && g < N) {
        int beg = offs[g], end = offs[g + 1];
        float acc0 = 0.f, acc1 = 0.f;
        int e = beg;
        for (; e + 1 < end; e += 2) {
            int s0 = csr[e], s1 = csr[e + 1];
            acc0 = fmaf(dinv[s0], t[s0 * 10 + j], acc0);
            acc1 = fmaf(dinv[s1], t[s1 * 10 + j], acc1);
        }
        if (e < end) {
            int s = csr[e];
            acc0 = fmaf(dinv[s], t[s * 10 + j], acc0);
        }
        float dn = dinv[g];
        float v = fmaf(dn, acc0 + acc1, dn * dn * t[g * 10 + j]) + b4[j];
        int gr = batch[g];
        atomicAdd(&lp[gr * 11 + j], v);
        if (j == 0) atomicAdd(&lp[gr * 11 + 10], 1.f);
    }
    __syncthreads();
    for (int i = tid; i < NGRAPH * 11; i += 256) {
        float v = lp[i];
        if (v != 0.f) atomicAdd(&pool[i], v);
    }
}

// ---------------- final divide ----------------
__global__ void final_k(const float* __restrict__ pool, float* __restrict__ out) {
    int i = blockIdx.x * blockDim.x + threadIdx.x;
    if (i >= NGRAPH * 10) return;
    int g = i / 10, f = i % 10;
    float c = pool[g * 11 + 10];
    out[i] = pool[g * 11 + f] / fmaxf(c, 1.f);
}

extern "C" void kernel_launch(void* const* d_in, const int* in_sizes, int n_in,
                              void* d_out, int out_size, void* d_ws, size_t ws_size,
                              hipStream_t stream) {
    const float* x   = (const float*)d_in[0];
    const float* pos = (const float*)d_in[1];
    const int* eidx  = (const int*)d_in[2];
    const int* batch = (const int*)d_in[3];
    const float* W1 = (const float*)d_in[4];  const float* b1 = (const float*)d_in[5];
    const float* W2 = (const float*)d_in[6];  const float* b2 = (const float*)d_in[7];
    const float* W3 = (const float*)d_in[8];  const float* b3 = (const float*)d_in[9];
    const float* W4 = (const float*)d_in[10]; const float* b4 = (const float*)d_in[11];

    const int N = in_sizes[0] / 8;
    const int E = in_sizes[2] / 2;
    const int* src = eidx;
    const int* dst = eidx + E;

    // bucket geometry (locality-structured: bucket = dst >> shift, <=256 buckets)
    int shift = 9;
    while ((((N + (1 << shift) - 1) >> shift)) > 256) ++shift;
    const int nbuckets = (N + (1 << shift) - 1) >> shift;
    const int capB = ((E / nbuckets) * 5) / 4 + 64;   // mean + ~23 sigma margin

    char* p = (char*)d_ws;
    auto alloc = [&](size_t bytes) { char* r = p; p += (bytes + 255) & ~255ull; return r; };
    int*   deg      = (int*)alloc((size_t)N * 4);
    int*   offs     = (int*)alloc((size_t)(N + 1) * 4);
    int*   cursor   = (int*)alloc((size_t)N * 4);
    int*   partials = (int*)alloc(512 * 4);
    int*   bcur     = (int*)alloc(256 * 4);
    float* dinv     = (float*)alloc((size_t)N * 4);
    int*   csr      = (int*)alloc((size_t)E * 4);
    uint2* bucketed = (uint2*)alloc(((size_t)nbuckets + 1) * capB * 8);  // +1 region padding
    float* bufX     = (float*)alloc((size_t)N * 64 * 4);
    float* bufY     = (float*)alloc((size_t)N * 64 * 4);
    float* bufZ     = (float*)alloc((size_t)N * 16 * 4);
    float* pool     = (float*)alloc(NGRAPH * 11 * 4);

    hipMemsetAsync(pool, 0, NGRAPH * 11 * 4, stream);

    concat_k<<<(N + 255) / 256, 256, 0, stream>>>(x, pos, bufZ, N);

    // CSR build: bucket-scatter -> LDS degree count -> scan -> LDS csr fill
    binit_k<<<1, 256, 0, stream>>>(bcur, nbuckets, capB);
    scatter_k<<<(E + 4095) / 4096, 256, 0, stream>>>(src, dst, bcur, bucketed, E, shift);
    bdeg_k<<<nbuckets, 256, 0, stream>>>(bucketed, bcur, deg, capB, N, shift);

    const int nb = (N + 511) / 512;
    scan1_k<<<nb, 512, 0, stream>>>(deg, offs, partials, N);
    scan2b_k<<<1, 512, 0, stream>>>(partials, nb);
    scan3_k<<<nb, 512, 0, stream>>>(offs, partials, cursor, N, E);
    dinv_k<<<(N + 255) / 256, 256, 0, stream>>>(deg, dinv, N);
    bfill_k<<<nbuckets, 256, 0, stream>>>(bucketed, bcur, offs, cursor, csr, capB, N, shift);

    auto cap = [](int t) { return t < 2048 ? t : 2048; };

    // Layer 1: agg16 (Z->X), gemm 16->32 +relu (X->Y)
    agg_k<16><<<(N * 4 + 255) / 256, 256, 0, stream>>>(bufZ, offs, csr, dinv, bufX, N);
    {
        int nt = (N + 63) / 64;
        gemm_k<16, 32, true, false><<<cap(nt), 256, 0, stream>>>(bufX, W1, b1, nullptr, bufY, N, nt);
    }
    // Layer 2: agg32 (Y->X), gemm 32->64 +relu (X->Y)
    agg_k<32><<<(N * 8 + 255) / 256, 256, 0, stream>>>(bufY, offs, csr, dinv, bufX, N);
    {
        int nt = (N + 31) / 32;
        gemm_k<32, 64, true, false><<<cap(nt), 256, 0, stream>>>(bufX, W2, b2, nullptr, bufY, N, nt);
    }
    // Layer 3+4a: agg64 (Y->X), gemm 64->128 +relu, fused @W4 -> 10 (X->Z)
    agg_k<64><<<(N * 16 + 255) / 256, 256, 0, stream>>>(bufY, offs, csr, dinv, bufX, N);
    {
        int nt = (N + 15) / 16;
        gemm_k<64, 128, true, true><<<cap(nt), 256, 0, stream>>>(bufX, W3, b3, W4, bufZ, N, nt);
    }
    // Layer 4b: agg10 + b4 + pool partials (Z -> pool)
    aggpool_k<<<(N + 24) / 25, 256, 0, stream>>>(bufZ, offs, csr, dinv, b4, batch, pool, N);
    final_k<<<3, 256, 0, stream>>>(pool, (float*)d_out);
}